// Round 5
// baseline (85.509 us; speedup 1.0000x reference)
//
#include <hip/hip_runtime.h>
#include <hip/hip_bf16.h>

#define P_ADC 64
#define M_SEN 256
#define B_BLK 32
#define BATCHN 4096

// Derived GEMM: Out[R=131072][128] = X[R][512] * W[512][128], W[k][p] = A[p][k]
#define GK 512
#define GN 128
#define GR (BATCHN * B_BLK)   // 131072 rows

typedef float  f32x4  __attribute__((ext_vector_type(4)));
typedef __bf16 bf16x8 __attribute__((ext_vector_type(8)));
typedef unsigned int u32x4 __attribute__((ext_vector_type(4)));

// ---------------------------------------------------------------------------
// Kernel 1: build the t<8 HALF of W in MFMA fragment order (64 KB).
// Fragment layout: wfrag[t][f][lane][j], t=0..7, f=0..7:
//   W[k][n],  n = f*16 + (lane&15),  g = lane>>4,
//   k = t*32 + (j>>2)*16 + g*4 + (j&3)        (k-slot permutation; both
//   operands use the same map so the MFMA contraction is unchanged)
// W[k][n] = A[n][k], quadrants: (n<64,k<256)=cos, (n<64,k>=256)=-sin,
//   (n>=64,k<256)=sin, (n>=64,k>=256)=cos, ang = -pv[n&63]*(k&255)*2pi/256.
// Symmetry used by the GEMM (k -> k+256 flips quadrant only):
//   frag(t+8, f)   = -frag(t, f+4)   (f<4)
//   frag(t+8, f+4) = +frag(t, f)     (f<4)
// so only t<8 is materialized.
// ---------------------------------------------------------------------------
__global__ void build_w_frags(const float* __restrict__ pv, __bf16* __restrict__ wfrag) {
    int tid = blockIdx.x * blockDim.x + threadIdx.x;
    if (tid >= 8 * 8 * 64) return;
    int lane = tid & 63;
    int f    = (tid >> 6) & 7;
    int t    = tid >> 9;          // 0..7
    int n    = f * 16 + (lane & 15);
    int g    = lane >> 4;
    int q    = n & 63;
    bool ph  = (n >= 64);
    float pq = pv[q];
    const float step = -0.02454369260617025967f; // -2*pi/256
    bf16x8 v;
#pragma unroll
    for (int j = 0; j < 8; ++j) {
        int k  = t * 32 + ((j >> 2) << 4) + g * 4 + (j & 3);   // k < 256 here
        float ang = pq * (float)k * step;
        float s, c;
        sincosf(ang, &s, &c);
        float a = ph ? s : c;     // k<256: n<64 -> cos, n>=64 -> sin
        v[j] = (__bf16)a;
    }
    *(bf16x8*)(wfrag + (size_t)tid * 8) = v;
}

// ---------------------------------------------------------------------------
// Kernel 2: 1024 thr = 16 waves = 8 row-stripes x 2 col-halves; wave does
// 16 rows x 64 cols (acc[4] = 16 VGPRs). LDS = 64 KB (t<8 frags) -> 2
// blocks/CU; __launch_bounds__(1024,8) caps VGPR at 64 -> 32 waves/CU.
// t>=8 K-steps reuse the t<8 frags via the signed symmetry above: col-half 0
// (n<64) uses frag(t-8, f+4) with NEGATED X fragment; col-half 1 (n>=64)
// uses frag(t-8, f-4) with the plain fragment.
// Swapped operands: A=W(LDS), B=X; D reg r = out col -> f32x4 stores.
// ---------------------------------------------------------------------------
__global__ __launch_bounds__(1024, 8) void analog_gemm(const float* __restrict__ X,
                                                       const __bf16* __restrict__ W,
                                                       float* __restrict__ out) {
    __shared__ __bf16 lw[8 * 8 * 64 * 8];   // 32768 bf16 = 64 KB

    const int tid = threadIdx.x;

    // Stage t<8 frags global->LDS: 4096 x 16B chunks, 1024 thr x 4 each.
    {
        const f32x4* src = (const f32x4*)W;
        f32x4* dst = (f32x4*)lw;
#pragma unroll
        for (int i = 0; i < 4; ++i)
            dst[i * 1024 + tid] = src[i * 1024 + tid];
    }
    __syncthreads();

    const int lane = tid & 63;
    const int wave = tid >> 6;         // 0..15
    const int rs   = wave >> 1;        // row-stripe 0..7
    const int ch   = wave & 1;         // col-half
    const int lr   = lane & 15;
    const int g    = lane >> 4;

    const long rowbase = (long)blockIdx.x * 128 + (long)rs * 16;
    const float* xp = X + (rowbase + lr) * (long)GK + g * 4;
    const bf16x8* wp = (const bf16x8*)lw + lane;    // + (t*8 + f)*64, t<8

    f32x4 acc[4];
#pragma unroll
    for (int f = 0; f < 4; ++f) acc[f] = (f32x4)0.0f;

    const int fb  = ch * 4;       // this wave's f-frags: fb..fb+3
    const int fbS = 4 - fb;       // frags used for t>=8 (swapped half)

    // t = 0..7: plain
#pragma unroll
    for (int t = 0; t < 8; ++t) {
        f32x4 xa = *(const f32x4*)(xp + t * 32);
        f32x4 xb = *(const f32x4*)(xp + t * 32 + 16);
        bf16x8 b;
#pragma unroll
        for (int j = 0; j < 4; ++j) { b[j] = (__bf16)xa[j]; b[4 + j] = (__bf16)xb[j]; }
#pragma unroll
        for (int f = 0; f < 4; ++f) {
            bf16x8 w = wp[(t * 8 + fb + f) * 64];
            acc[f] = __builtin_amdgcn_mfma_f32_16x16x32_bf16(w, b, acc[f], 0, 0, 0);
        }
    }

    // t = 8..15: reuse t-8 frags of the OTHER col-half; negate B if ch==0
#pragma unroll
    for (int t = 8; t < 16; ++t) {
        f32x4 xa = *(const f32x4*)(xp + t * 32);
        f32x4 xb = *(const f32x4*)(xp + t * 32 + 16);
        bf16x8 b;
#pragma unroll
        for (int j = 0; j < 4; ++j) { b[j] = (__bf16)xa[j]; b[4 + j] = (__bf16)xb[j]; }
        if (ch == 0) {  // wave-uniform; negate all 8 bf16 via sign-bit xor
            u32x4 u = __builtin_bit_cast(u32x4, b);
#pragma unroll
            for (int j = 0; j < 4; ++j) u[j] ^= 0x80008000u;
            b = __builtin_bit_cast(bf16x8, u);
        }
#pragma unroll
        for (int f = 0; f < 4; ++f) {
            bf16x8 w = wp[((t - 8) * 8 + fbS + f) * 64];
            acc[f] = __builtin_amdgcn_mfma_f32_16x16x32_bf16(w, b, acc[f], 0, 0, 0);
        }
    }

    // lane stores row rowbase+lr, cols (fb+f)*16 + g*4 .. +3
    float* op = out + (rowbase + lr) * (long)GN + fb * 16 + g * 4;
#pragma unroll
    for (int f = 0; f < 4; ++f)
        __builtin_nontemporal_store(acc[f], (f32x4*)(op + f * 16));
}

extern "C" void kernel_launch(void* const* d_in, const int* in_sizes, int n_in,
                              void* d_out, int out_size, void* d_ws, size_t ws_size,
                              hipStream_t stream) {
    const float* x  = (const float*)d_in[0];
    const float* pv = (const float*)d_in[1];
    float* out      = (float*)d_out;
    __bf16* wfrag   = (__bf16*)d_ws;   // 8*8*64*8*2 = 65536 bytes used

    hipLaunchKernelGGL(build_w_frags, dim3(16), dim3(256), 0, stream, pv, wfrag);
    hipLaunchKernelGGL(analog_gemm, dim3(GR / 128), dim3(1024), 0, stream, x, wfrag, out);
}